// Round 1
// baseline (303.892 us; speedup 1.0000x reference)
//
#include <hip/hip_runtime.h>
#include <stdint.h>

// ---------------- types / helpers ----------------
typedef float  f32x4  __attribute__((ext_vector_type(4)));
typedef short  bf16x8 __attribute__((ext_vector_type(8)));

#define NCOL 800    // L*NH output cols of o_h
#define NPAD 896    // padded to 7*128
#define KDIM 6400   // L*D
#define KTOT 1824   // NV*D + NH*L

__device__ __forceinline__ unsigned short f2bf(float f) {
  unsigned int u = __float_as_uint(f);
  return (unsigned short)((u + 0x7FFFu + ((u >> 16) & 1u)) >> 16);  // RNE
}
__device__ __forceinline__ float bf2f(unsigned short s) {
  return __uint_as_float(((unsigned int)s) << 16);
}
__device__ __forceinline__ void gload16(const void* g, void* lds) {
  __builtin_amdgcn_global_load_lds(
      (const __attribute__((address_space(1))) unsigned int*)g,
      (__attribute__((address_space(3))) unsigned int*)lds, 16, 0, 0);
}

// ---------------- K1a: gather item_emb -> Ebf[b][t][d] bf16 ----------------
__global__ void k_gather_e(const int* __restrict__ iseq,
                           const float* __restrict__ iemb,
                           unsigned short* __restrict__ Ebf) {
  int b = blockIdx.x;
  for (int idx = threadIdx.x; idx < 1600; idx += 256) {  // 50 rows * 32 float4
    int tt = idx >> 5, dq = idx & 31;
    int row = iseq[b * 50 + tt];
    float4 v = *reinterpret_cast<const float4*>(iemb + (size_t)row * 128 + dq * 4);
    unsigned int lo = (unsigned int)f2bf(v.x) | ((unsigned int)f2bf(v.y) << 16);
    unsigned int hi = (unsigned int)f2bf(v.z) | ((unsigned int)f2bf(v.w) << 16);
    *reinterpret_cast<uint2*>(Ebf + (size_t)b * KDIM + tt * 128 + dq * 4) = make_uint2(lo, hi);
  }
}

// ---------------- K1b: pack Wh -> Wbf[n=(l,h)][k=(i,d)] bf16, rows padded to 896 ----------------
__global__ void k_pack_w(const float* __restrict__ Wh, unsigned short* __restrict__ Wbf) {
  int n = blockIdx.x;  // 0..895
  unsigned short* dst = Wbf + (size_t)n * KDIM;
  if (n >= NCOL) {
    uint4 z = make_uint4(0, 0, 0, 0);
    for (int idx = threadIdx.x; idx < KDIM / 8; idx += 256)
      reinterpret_cast<uint4*>(dst)[idx] = z;
  } else {
    const float* src = Wh + (size_t)n * KDIM;  // ((l*16+h)*50 + i)*128 + d == n*6400 + k : pure row copy
    for (int idx = threadIdx.x; idx < KDIM / 4; idx += 256) {
      float4 v = reinterpret_cast<const float4*>(src)[idx];
      unsigned int lo = (unsigned int)f2bf(v.x) | ((unsigned int)f2bf(v.y) << 16);
      unsigned int hi = (unsigned int)f2bf(v.z) | ((unsigned int)f2bf(v.w) << 16);
      reinterpret_cast<uint2*>(dst)[idx] = make_uint2(lo, hi);
    }
  }
}

// ---------------- K2v: o_v[b][v*128+d] = sum_t E*Wv + bv ----------------
__global__ void k_ov(const unsigned short* __restrict__ Ebf,
                     const float* __restrict__ Wv, const float* __restrict__ bv,
                     float* __restrict__ o_v) {
  int b = blockIdx.x;
  const unsigned short* e = Ebf + (size_t)b * KDIM;
  for (int rep = 0; rep < 4; rep++) {
    int idx = rep * 256 + threadIdx.x;
    int v = idx >> 7, d = idx & 127;
    float acc = bv[v];
    for (int tt = 0; tt < 50; tt++)
      acc += bf2f(e[tt * 128 + d]) * Wv[v * 50 + tt];
    o_v[(size_t)b * 1024 + idx] = acc;
  }
}

// ---------------- K2: conv-as-shifted-GEMM + relu + masked max (atomicMax) ----------------
// grid (8 mtiles, 7 ntiles, 17 s-chunk slots); 256 thr = 4 waves (2x2), 4x4 reg-block, BK=64 dbuf
__launch_bounds__(256, 2)
__global__ void k_conv(const unsigned short* __restrict__ Ebf,
                       const unsigned short* __restrict__ Wbf,
                       const float* __restrict__ bh,
                       unsigned int* __restrict__ o_h) {
  __shared__ alignas(16) unsigned short As[2][128 * 64];
  __shared__ alignas(16) unsigned short Bs[2][128 * 64];

  const int tid = threadIdx.x;
  const int wid = tid >> 6, lane = tid & 63;
  const int r = lane & 15, kg = lane >> 4;
  const int wm = wid >> 1, wn = wid & 1;
  const int mt = blockIdx.x, nt = blockIdx.y, sc = blockIdx.z;

  const int lmin = nt * 8;
  const int lmax = min(nt * 8 + 7, 49);
  const int shi = 49 - lmin;                       // max valid s for this n-tile
  const int chunk = (nt < 2) ? 4 : ((nt < 5) ? 2 : 1);  // load-balance table
  const int s0 = sc * chunk;
  if (s0 > shi) return;
  const int s1 = min(s0 + chunk - 1, shi);

  const int Rloc = lane >> 3;   // staging: row-in-8 per lane
  const int cph = lane & 7;     // staging: physical 16B chunk per lane

  // per-lane epilogue constants
  float bhv[4]; int ls[4];
#pragma unroll
  for (int n = 0; n < 4; n++) {
    int ng = nt * 128 + wn * 64 + n * 16 + r;
    bhv[n] = (ng < NCOL) ? bh[ng] : 0.f;
    ls[n] = ng >> 4;
  }

  const f32x4 z4 = {0.f, 0.f, 0.f, 0.f};
  f32x4 acc[4][4], vmax[4][4];
#pragma unroll
  for (int m = 0; m < 4; m++)
#pragma unroll
    for (int n = 0; n < 4; n++) { acc[m][n] = z4; vmax[m][n] = z4; }

  // swizzled staging: LDS phys chunk p of row R holds logical chunk (p ^ (R&7))
  auto STAGE = [&](int buf, int s, int kk) {
    const int Rb = wid * 32;
#pragma unroll
    for (int ia = 0; ia < 4; ia++) {
      int R = Rb + ia * 8 + Rloc;
      const unsigned short* src = Ebf + (size_t)(mt * 128 + R) * KDIM + s * 128 + kk * 64
                                      + ((cph ^ (R & 7)) * 8);
      gload16(src, &As[buf][(Rb + ia * 8) * 64]);
    }
#pragma unroll
    for (int ia = 0; ia < 4; ia++) {
      int R = Rb + ia * 8 + Rloc;
      const unsigned short* src = Wbf + (size_t)(nt * 128 + R) * KDIM + kk * 64
                                      + ((cph ^ (R & 7)) * 8);
      gload16(src, &Bs[buf][(Rb + ia * 8) * 64]);
    }
  };

  auto COMPUTE = [&](int buf) {
#pragma unroll
    for (int ks = 0; ks < 2; ks++) {
      bf16x8 af[4], bfr[4];
      const int sw = ((ks * 4 + kg) ^ (r & 7)) * 8;  // swizzled read offset (shorts)
#pragma unroll
      for (int m = 0; m < 4; m++)
        af[m] = *reinterpret_cast<const bf16x8*>(&As[buf][(wm * 64 + m * 16 + r) * 64 + sw]);
#pragma unroll
      for (int n = 0; n < 4; n++)
        bfr[n] = *reinterpret_cast<const bf16x8*>(&Bs[buf][(wn * 64 + n * 16 + r) * 64 + sw]);
#pragma unroll
      for (int m = 0; m < 4; m++)
#pragma unroll
        for (int n = 0; n < 4; n++)
          acc[m][n] = __builtin_amdgcn_mfma_f32_16x16x32_bf16(af[m], bfr[n], acc[m][n], 0, 0, 0);
    }
  };

  int cur = 0;
  STAGE(0, s0, 0);
  __syncthreads();

  for (int s = s0; s <= s1; s++) {
    const int nk = min(50 - s, lmax + 1) * 2;  // BK-steps (zero-masked i>l terms are free/correct)
    for (int kk = 0; kk < nk; kk++) {
      const bool more = (kk + 1 < nk) || (s < s1);
      if (more) {
        int ns  = (kk + 1 < nk) ? s : s + 1;
        int nkk = (kk + 1 < nk) ? kk + 1 : 0;
        STAGE(cur ^ 1, ns, nkk);
      }
      COMPUTE(cur);
      __syncthreads();
      cur ^= 1;
    }
    // epilogue for this s: relu(conv+bh), masked max over s
#pragma unroll
    for (int m = 0; m < 4; m++)
#pragma unroll
      for (int n = 0; n < 4; n++) {
        const bool valid = (s <= 49 - ls[n]);
#pragma unroll
        for (int q = 0; q < 4; q++) {
          float v = fmaxf(acc[m][n][q] + bhv[n], 0.f);
          if (valid) vmax[m][n][q] = fmaxf(vmax[m][n][q], v);
        }
        acc[m][n] = z4;
      }
  }

  // one atomicMax per output element per s-chunk (f32>=0 compares as uint)
#pragma unroll
  for (int m = 0; m < 4; m++) {
    int b = mt * 128 + wm * 64 + m * 16 + kg * 4;
#pragma unroll
    for (int n = 0; n < 4; n++) {
      int ng = nt * 128 + wn * 64 + n * 16 + r;
      if (ng < NCOL) {
#pragma unroll
        for (int q = 0; q < 4; q++)
          atomicMax(&o_h[(size_t)(b + q) * NCOL + ng], __float_as_uint(vmax[m][n][q]));
      }
    }
  }
}

// ---------------- K3: z = relu([o_v|o_h] @ fcW + fcb) ----------------
__global__ void k_fc(const float* __restrict__ o_v, const float* __restrict__ o_h,
                     const float* __restrict__ fcW, const float* __restrict__ fcb,
                     float* __restrict__ out) {
  __shared__ float olds[KTOT];
  __shared__ float red[8][128];
  int b = blockIdx.x, t = threadIdx.x;
  for (int idx = t; idx < 1024; idx += 256) olds[idx] = o_v[(size_t)b * 1024 + idx];
  for (int idx = t; idx < 800; idx += 256)  olds[1024 + idx] = o_h[(size_t)b * 800 + idx];
  __syncthreads();
  int dg = (t & 31) * 4, kseg = t >> 5;
  int k0 = kseg * 228, k1 = min(k0 + 228, KTOT);
  float a0 = 0, a1 = 0, a2 = 0, a3 = 0;
  for (int k = k0; k < k1; k++) {
    float ov = olds[k];
    float4 w = *reinterpret_cast<const float4*>(fcW + (size_t)k * 128 + dg);
    a0 += ov * w.x; a1 += ov * w.y; a2 += ov * w.z; a3 += ov * w.w;
  }
  red[kseg][dg] = a0; red[kseg][dg + 1] = a1; red[kseg][dg + 2] = a2; red[kseg][dg + 3] = a3;
  __syncthreads();
  if (t < 128) {
    float s = fcb[t];
#pragma unroll
    for (int i = 0; i < 8; i++) s += red[i][t];
    out[(size_t)b * 256 + t] = fmaxf(s, 0.f);
  }
}

// ---------------- K4: P_u copy ----------------
__global__ void k_pu(const int* __restrict__ uid, const float* __restrict__ uemb,
                     float* __restrict__ out) {
  int b = blockIdx.x, d = threadIdx.x;
  out[(size_t)b * 256 + 128 + d] = uemb[(size_t)uid[b] * 128 + d];
}

// ---------------- launch ----------------
extern "C" void kernel_launch(void* const* d_in, const int* in_sizes, int n_in,
                              void* d_out, int out_size, void* d_ws, size_t ws_size,
                              hipStream_t stream) {
  const int*   uid  = (const int*)d_in[0];
  const int*   iseq = (const int*)d_in[1];
  const float* uemb = (const float*)d_in[2];
  const float* iemb = (const float*)d_in[3];
  const float* Wv   = (const float*)d_in[4];
  const float* bv   = (const float*)d_in[5];
  const float* Wh   = (const float*)d_in[6];
  const float* bh   = (const float*)d_in[7];
  const float* fcW  = (const float*)d_in[8];
  const float* fcb  = (const float*)d_in[9];
  float* out = (float*)d_out;
  char* ws = (char*)d_ws;

  float*          o_v = (float*)(ws);                         // 4,194,304 B
  unsigned int*   o_h = (unsigned int*)(ws + 4194304);        // 3,276,800 B
  unsigned short* Ebf = (unsigned short*)(ws + 7471104);      // 13,107,200 B
  unsigned short* Wbf = (unsigned short*)(ws + 20578304);     // 11,468,800 B  (total ~32 MB)

  hipMemsetAsync(o_h, 0, (size_t)1024 * NCOL * 4, stream);
  k_gather_e<<<dim3(1024), 256, 0, stream>>>(iseq, iemb, Ebf);
  k_pack_w  <<<dim3(NPAD), 256, 0, stream>>>(Wh, Wbf);
  k_ov      <<<dim3(1024), 256, 0, stream>>>(Ebf, Wv, bv, o_v);
  k_conv    <<<dim3(8, 7, 17), 256, 0, stream>>>(Ebf, Wbf, bh, o_h);
  k_fc      <<<dim3(1024), 256, 0, stream>>>(o_v, (const float*)o_h, fcW, fcb, out);
  k_pu      <<<dim3(1024), 128, 0, stream>>>(uid, uemb, out);
}

// Round 2
// 220.284 us; speedup vs baseline: 1.3795x; 1.3795x over previous
//
#include <hip/hip_runtime.h>
#include <stdint.h>

// ---------------- types / helpers ----------------
typedef float  f32x4  __attribute__((ext_vector_type(4)));
typedef short  bf16x8 __attribute__((ext_vector_type(8)));

#define NCOL 800    // L*NH output cols of o_h
#define NPAD 896    // padded to 7*128
#define KDIM 6400   // L*D
#define KFC  1856   // fc K = 1824 padded to 29*64

__device__ __forceinline__ unsigned short f2bf(float f) {
  unsigned int u = __float_as_uint(f);
  return (unsigned short)((u + 0x7FFFu + ((u >> 16) & 1u)) >> 16);  // RNE
}
__device__ __forceinline__ float bf2f(unsigned short s) {
  return __uint_as_float(((unsigned int)s) << 16);
}
__device__ __forceinline__ void gload16(const void* g, void* lds) {
  __builtin_amdgcn_global_load_lds(
      (const __attribute__((address_space(1))) unsigned int*)g,
      (__attribute__((address_space(3))) unsigned int*)lds, 16, 0, 0);
}

// ---------------- K1a: gather item_emb -> Ebf[b][t][d] bf16 ----------------
__global__ void k_gather_e(const int* __restrict__ iseq,
                           const float* __restrict__ iemb,
                           unsigned short* __restrict__ Ebf) {
  int b = blockIdx.x;
  for (int idx = threadIdx.x; idx < 1600; idx += 256) {  // 50 rows * 32 float4
    int tt = idx >> 5, dq = idx & 31;
    int row = iseq[b * 50 + tt];
    float4 v = *reinterpret_cast<const float4*>(iemb + (size_t)row * 128 + dq * 4);
    unsigned int lo = (unsigned int)f2bf(v.x) | ((unsigned int)f2bf(v.y) << 16);
    unsigned int hi = (unsigned int)f2bf(v.z) | ((unsigned int)f2bf(v.w) << 16);
    *reinterpret_cast<uint2*>(Ebf + (size_t)b * KDIM + tt * 128 + dq * 4) = make_uint2(lo, hi);
  }
}

// ---------------- K1b: pack Wh -> Wbf[n=(l,h)][k=(i,d)] bf16, rows padded to 896 ----------------
__global__ void k_pack_w(const float* __restrict__ Wh, unsigned short* __restrict__ Wbf) {
  int n = blockIdx.x;  // 0..895
  unsigned short* dst = Wbf + (size_t)n * KDIM;
  if (n >= NCOL) {
    uint4 z = make_uint4(0, 0, 0, 0);
    for (int idx = threadIdx.x; idx < KDIM / 8; idx += 256)
      reinterpret_cast<uint4*>(dst)[idx] = z;
  } else {
    const float* src = Wh + (size_t)n * KDIM;  // pure row copy: ((l*16+h)*50+i)*128+d == n*6400+k
    for (int idx = threadIdx.x; idx < KDIM / 4; idx += 256) {
      float4 v = reinterpret_cast<const float4*>(src)[idx];
      unsigned int lo = (unsigned int)f2bf(v.x) | ((unsigned int)f2bf(v.y) << 16);
      unsigned int hi = (unsigned int)f2bf(v.z) | ((unsigned int)f2bf(v.w) << 16);
      reinterpret_cast<uint2*>(dst)[idx] = make_uint2(lo, hi);
    }
  }
}

// ---------------- K2v: o_bf[b][v*128+d] = bf16(sum_t E*Wv + bv) ----------------
__global__ void k_ovbf(const unsigned short* __restrict__ Ebf,
                       const float* __restrict__ Wv, const float* __restrict__ bv,
                       unsigned short* __restrict__ o_bf) {
  int b = blockIdx.x;
  const unsigned short* e = Ebf + (size_t)b * KDIM;
  for (int rep = 0; rep < 2; rep++) {
    int idx2 = rep * 256 + threadIdx.x;   // uint index, 0..511
    int v = idx2 >> 6;
    int dp = (idx2 & 63) * 2;
    float a0 = bv[v], a1 = a0;
    for (int tt = 0; tt < 50; tt++) {
      float w = Wv[v * 50 + tt];
      a0 += bf2f(e[tt * 128 + dp]) * w;
      a1 += bf2f(e[tt * 128 + dp + 1]) * w;
    }
    unsigned int pk = (unsigned int)f2bf(a0) | ((unsigned int)f2bf(a1) << 16);
    reinterpret_cast<unsigned int*>(o_bf + (size_t)b * KFC)[idx2] = pk;
  }
}

// ---------------- K2: conv-as-shifted-GEMM + relu + masked max (atomicMax) ----------------
// single-buffer m97-style: STAGE -> barrier -> COMPUTE -> barrier. 32KB LDS -> ~3 blocks/CU.
__launch_bounds__(256, 3)
__global__ void k_conv(const unsigned short* __restrict__ Ebf,
                       const unsigned short* __restrict__ Wbf,
                       const float* __restrict__ bh,
                       unsigned int* __restrict__ o_h) {
  __shared__ alignas(16) unsigned short As[128 * 64];
  __shared__ alignas(16) unsigned short Bs[128 * 64];

  const int tid = threadIdx.x;
  const int wid = tid >> 6, lane = tid & 63;
  const int r = lane & 15, kg = lane >> 4;
  const int wm = wid >> 1, wn = wid & 1;
  const int mt = blockIdx.x, nt = blockIdx.y, sc = blockIdx.z;

  const int lmin = nt * 8;
  const int lmax = min(nt * 8 + 7, 49);
  const int shi = 49 - lmin;                         // max valid s for this n-tile
  // balanced work: chunk*(lmax+1)*2 ~ 96-128 K-steps per block
  const int chunk_tab[7] = {6, 3, 2, 2, 1, 1, 1};
  const int chunk = chunk_tab[nt];
  const int s0 = sc * chunk;
  if (s0 > shi) return;
  const int s1 = min(s0 + chunk - 1, shi);

  const int Rloc = lane >> 3;   // staging: row-in-8 per lane
  const int cph = lane & 7;     // staging: physical 16B chunk per lane

  float bhv[4]; int ls[4];
#pragma unroll
  for (int n = 0; n < 4; n++) {
    int ng = nt * 128 + wn * 64 + n * 16 + r;
    bhv[n] = (ng < NCOL) ? bh[ng] : 0.f;
    ls[n] = ng >> 4;
  }

  const f32x4 z4 = {0.f, 0.f, 0.f, 0.f};
  f32x4 acc[4][4], vmax[4][4];
#pragma unroll
  for (int m = 0; m < 4; m++)
#pragma unroll
    for (int n = 0; n < 4; n++) { acc[m][n] = z4; vmax[m][n] = z4; }

  // swizzled staging: LDS phys chunk p of row R holds logical chunk (p ^ (R&7))
  auto STAGE = [&](int s, int kk) {
    const int Rb = wid * 32;
#pragma unroll
    for (int ia = 0; ia < 4; ia++) {
      int R = Rb + ia * 8 + Rloc;
      const unsigned short* src = Ebf + (size_t)(mt * 128 + R) * KDIM + s * 128 + kk * 64
                                      + ((cph ^ (R & 7)) * 8);
      gload16(src, &As[(Rb + ia * 8) * 64]);
    }
#pragma unroll
    for (int ia = 0; ia < 4; ia++) {
      int R = Rb + ia * 8 + Rloc;
      const unsigned short* src = Wbf + (size_t)(nt * 128 + R) * KDIM + kk * 64
                                      + ((cph ^ (R & 7)) * 8);
      gload16(src, &Bs[(Rb + ia * 8) * 64]);
    }
  };

  auto COMPUTE = [&]() {
#pragma unroll
    for (int ks = 0; ks < 2; ks++) {
      bf16x8 af[4], bfr[4];
      const int sw = ((ks * 4 + kg) ^ (r & 7)) * 8;  // swizzled read offset (shorts)
#pragma unroll
      for (int m = 0; m < 4; m++)
        af[m] = *reinterpret_cast<const bf16x8*>(&As[(wm * 64 + m * 16 + r) * 64 + sw]);
#pragma unroll
      for (int n = 0; n < 4; n++)
        bfr[n] = *reinterpret_cast<const bf16x8*>(&Bs[(wn * 64 + n * 16 + r) * 64 + sw]);
#pragma unroll
      for (int m = 0; m < 4; m++)
#pragma unroll
        for (int n = 0; n < 4; n++)
          acc[m][n] = __builtin_amdgcn_mfma_f32_16x16x32_bf16(af[m], bfr[n], acc[m][n], 0, 0, 0);
    }
  };

  for (int s = s0; s <= s1; s++) {
    const int nk = min(50 - s, lmax + 1) * 2;  // BK-steps (zero-masked i>l terms are free/correct)
    for (int kk = 0; kk < nk; kk++) {
      STAGE(s, kk);
      __syncthreads();
      COMPUTE();
      __syncthreads();
    }
    // epilogue for this s: relu(conv+bh), masked max over s
#pragma unroll
    for (int m = 0; m < 4; m++)
#pragma unroll
      for (int n = 0; n < 4; n++) {
        const bool valid = (s <= 49 - ls[n]);
#pragma unroll
        for (int q = 0; q < 4; q++) {
          float v = fmaxf(acc[m][n][q] + bhv[n], 0.f);
          if (valid) vmax[m][n][q] = fmaxf(vmax[m][n][q], v);
        }
        acc[m][n] = z4;
      }
  }

  // one atomicMax per output element per s-chunk (f32>=0 compares as uint)
#pragma unroll
  for (int m = 0; m < 4; m++) {
    int b = mt * 128 + wm * 64 + m * 16 + kg * 4;
#pragma unroll
    for (int n = 0; n < 4; n++) {
      int ng = nt * 128 + wn * 64 + n * 16 + r;
      if (ng < NCOL) {
#pragma unroll
        for (int q = 0; q < 4; q++)
          atomicMax(&o_h[(size_t)(b + q) * NCOL + ng], __float_as_uint(vmax[m][n][q]));
      }
    }
  }
}

// ---------------- K2c: o_h u32(f32) -> bf16 into o_bf[:,1024:1856], zero pad ----------------
__global__ void k_cvt_oh(const unsigned int* __restrict__ o_h,
                         unsigned short* __restrict__ o_bf) {
  int b = blockIdx.x;
  const unsigned int* src = o_h + (size_t)b * NCOL;
  unsigned int* dst = reinterpret_cast<unsigned int*>(o_bf + (size_t)b * KFC + 1024);
  for (int i = threadIdx.x; i < 416; i += 256) {  // 832 shorts = cols 1024..1855
    int j0 = 2 * i, j1 = j0 + 1;
    unsigned int lo = (j0 < NCOL) ? f2bf(__uint_as_float(src[j0])) : 0;
    unsigned int hi = (j1 < NCOL) ? f2bf(__uint_as_float(src[j1])) : 0;
    dst[i] = lo | (hi << 16);
  }
}

// ---------------- K3a: fcW [k][d] f32 -> Bt [d][k] bf16 (K padded to 1856) ----------------
__global__ void k_pack_fcwT(const float* __restrict__ fcW, unsigned short* __restrict__ Bt) {
  __shared__ float tile[32][33];
  int k0 = blockIdx.x * 32, d0 = blockIdx.y * 32;
  int tx = threadIdx.x & 31, ty = threadIdx.x >> 5;  // 32 x 8
#pragma unroll
  for (int it = 0; it < 4; it++) {
    int k = k0 + ty + it * 8;
    tile[ty + it * 8][tx] = (k < 1824) ? fcW[(size_t)k * 128 + d0 + tx] : 0.f;
  }
  __syncthreads();
#pragma unroll
  for (int it = 0; it < 4; it++) {
    int d = d0 + ty + it * 8;
    Bt[(size_t)d * KFC + k0 + tx] = f2bf(tile[tx][ty + it * 8]);
  }
}

// ---------------- K3: z = relu(o_bf @ Bt^T + fcb) via MFMA; M=1024,N=128,K=1856 ----------------
__launch_bounds__(256, 3)
__global__ void k_fc_mfma(const unsigned short* __restrict__ o_bf,
                          const unsigned short* __restrict__ Bt,
                          const float* __restrict__ fcb,
                          float* __restrict__ out) {
  __shared__ alignas(16) unsigned short As[128 * 64];
  __shared__ alignas(16) unsigned short Bs[128 * 64];

  const int tid = threadIdx.x;
  const int wid = tid >> 6, lane = tid & 63;
  const int r = lane & 15, kg = lane >> 4;
  const int wm = wid >> 1, wn = wid & 1;
  const int mt = blockIdx.x;

  const int Rloc = lane >> 3;
  const int cph = lane & 7;

  float fb[4];
#pragma unroll
  for (int n = 0; n < 4; n++) fb[n] = fcb[wn * 64 + n * 16 + r];

  const f32x4 z4 = {0.f, 0.f, 0.f, 0.f};
  f32x4 acc[4][4];
#pragma unroll
  for (int m = 0; m < 4; m++)
#pragma unroll
    for (int n = 0; n < 4; n++) acc[m][n] = z4;

  auto STAGE = [&](int kk) {
    const int Rb = wid * 32;
#pragma unroll
    for (int ia = 0; ia < 4; ia++) {
      int R = Rb + ia * 8 + Rloc;
      const unsigned short* src = o_bf + (size_t)(mt * 128 + R) * KFC + kk * 64
                                       + ((cph ^ (R & 7)) * 8);
      gload16(src, &As[(Rb + ia * 8) * 64]);
    }
#pragma unroll
    for (int ia = 0; ia < 4; ia++) {
      int R = Rb + ia * 8 + Rloc;
      const unsigned short* src = Bt + (size_t)R * KFC + kk * 64 + ((cph ^ (R & 7)) * 8);
      gload16(src, &Bs[(Rb + ia * 8) * 64]);
    }
  };

  auto COMPUTE = [&]() {
#pragma unroll
    for (int ks = 0; ks < 2; ks++) {
      bf16x8 af[4], bfr[4];
      const int sw = ((ks * 4 + kg) ^ (r & 7)) * 8;
#pragma unroll
      for (int m = 0; m < 4; m++)
        af[m] = *reinterpret_cast<const bf16x8*>(&As[(wm * 64 + m * 16 + r) * 64 + sw]);
#pragma unroll
      for (int n = 0; n < 4; n++)
        bfr[n] = *reinterpret_cast<const bf16x8*>(&Bs[(wn * 64 + n * 16 + r) * 64 + sw]);
#pragma unroll
      for (int m = 0; m < 4; m++)
#pragma unroll
        for (int n = 0; n < 4; n++)
          acc[m][n] = __builtin_amdgcn_mfma_f32_16x16x32_bf16(af[m], bfr[n], acc[m][n], 0, 0, 0);
    }
  };

  for (int kk = 0; kk < KFC / 64; kk++) {  // 29 steps
    STAGE(kk);
    __syncthreads();
    COMPUTE();
    __syncthreads();
  }

#pragma unroll
  for (int m = 0; m < 4; m++) {
    int b = mt * 128 + wm * 64 + m * 16 + kg * 4;
#pragma unroll
    for (int n = 0; n < 4; n++) {
      int d = wn * 64 + n * 16 + r;
#pragma unroll
      for (int q = 0; q < 4; q++)
        out[(size_t)(b + q) * 256 + d] = fmaxf(acc[m][n][q] + fb[n], 0.f);
    }
  }
}

// ---------------- K4: P_u copy ----------------
__global__ void k_pu(const int* __restrict__ uid, const float* __restrict__ uemb,
                     float* __restrict__ out) {
  int b = blockIdx.x, d = threadIdx.x;
  out[(size_t)b * 256 + 128 + d] = uemb[(size_t)uid[b] * 128 + d];
}

// ---------------- launch ----------------
extern "C" void kernel_launch(void* const* d_in, const int* in_sizes, int n_in,
                              void* d_out, int out_size, void* d_ws, size_t ws_size,
                              hipStream_t stream) {
  const int*   uid  = (const int*)d_in[0];
  const int*   iseq = (const int*)d_in[1];
  const float* uemb = (const float*)d_in[2];
  const float* iemb = (const float*)d_in[3];
  const float* Wv   = (const float*)d_in[4];
  const float* bv   = (const float*)d_in[5];
  const float* Wh   = (const float*)d_in[6];
  const float* bh   = (const float*)d_in[7];
  const float* fcW  = (const float*)d_in[8];
  const float* fcb  = (const float*)d_in[9];
  float* out = (float*)d_out;
  char* ws = (char*)d_ws;

  // layout (27.9 MB total; o_bf/Bt alias Wbf, which is dead after k_conv)
  unsigned int*   o_h = (unsigned int*)(ws);                  //  3,276,800 B
  unsigned short* Ebf = (unsigned short*)(ws + 3276800);      // 13,107,200 B
  unsigned short* Wbf = (unsigned short*)(ws + 16384000);     // 11,468,800 B
  unsigned short* o_bf = (unsigned short*)(ws + 16384000);    //  3,801,088 B (alias)
  unsigned short* Bt   = (unsigned short*)(ws + 20185088);    //    475,136 B (alias)

  hipMemsetAsync(o_h, 0, (size_t)1024 * NCOL * 4, stream);
  k_gather_e <<<dim3(1024), 256, 0, stream>>>(iseq, iemb, Ebf);
  k_pack_w   <<<dim3(NPAD), 256, 0, stream>>>(Wh, Wbf);
  k_conv     <<<dim3(8, 7, 18), 256, 0, stream>>>(Ebf, Wbf, bh, o_h);
  k_ovbf     <<<dim3(1024), 256, 0, stream>>>(Ebf, Wv, bv, o_bf);   // after k_conv: o_bf aliases Wbf
  k_cvt_oh   <<<dim3(1024), 256, 0, stream>>>(o_h, o_bf);
  k_pack_fcwT<<<dim3(58, 4), 256, 0, stream>>>(fcW, Bt);
  k_fc_mfma  <<<dim3(8), 256, 0, stream>>>(o_bf, Bt, fcb, out);
  k_pu       <<<dim3(1024), 128, 0, stream>>>(uid, uemb, out);
}